// Round 2
// baseline (745.673 us; speedup 1.0000x reference)
//
#include <hip/hip_runtime.h>
#include <hip/hip_bf16.h>

#define N_NODES 50000
#define K_NBR   16
#define DIN     128
#define DOUT    64

typedef __hip_bfloat16 bf16;

__device__ __forceinline__ float b2f(bf16 v) { return __bfloat162float(v); }
__device__ __forceinline__ float sigmoidf_(float x) { return 1.0f / (1.0f + __expf(-x)); }

template <typename T> __device__ __forceinline__ float ld(const T* p, size_t i);
template <> __device__ __forceinline__ float ld<float>(const float* p, size_t i) { return p[i]; }
template <> __device__ __forceinline__ float ld<bf16>(const bf16* p, size_t i)   { return b2f(p[i]); }

template <typename T> __device__ __forceinline__ void st(T* p, size_t i, float v);
template <> __device__ __forceinline__ void st<float>(float* p, size_t i, float v) { p[i] = v; }
template <> __device__ __forceinline__ void st<bf16>(bf16* p, size_t i, float v)   { p[i] = __float2bfloat16(v); }

// ---------------------------------------------------------------------------
// Dtype detector: view input as 16-bit words. For a true-bf16 array, the even
// (low-half-of-dword) elements are sane bf16 gaussians (exp in [112,142]).
// For an f32 array, low halves are mantissa garbage (~12% in range).
// flag: 1 = float32 data, 0 = bf16 data.
// ---------------------------------------------------------------------------
__global__ void detect_kernel(const unsigned short* __restrict__ x, int* __restrict__ flag)
{
    __shared__ int cnt;
    if (threadIdx.x == 0) cnt = 0;
    __syncthreads();
    int c = 0;
#pragma unroll
    for (int i = 0; i < 16; ++i) {
        unsigned short w = x[(size_t)(threadIdx.x * 16 + i) * 2];  // low half-word
        int e = (w >> 7) & 0xFF;
        c += (e >= 112 && e <= 142) ? 1 : 0;
    }
    atomicAdd(&cnt, c);
    __syncthreads();
    if (threadIdx.x == 0) *flag = (cnt >= 2048) ? 0 : 1;
}

// ---------------------------------------------------------------------------
// Pass A body: xn = x @ W_e1 (f32), h[:, :64] = sigmoid(x @ W_s1) (bf16)
// 1 wave per node, lane = output dim d.
// ---------------------------------------------------------------------------
template <typename T>
__device__ __forceinline__ void lin1_body(
    const T* __restrict__ x, const T* __restrict__ We, const T* __restrict__ Ws,
    float* __restrict__ xn, bf16* __restrict__ h)
{
    __shared__ float xrow[4][DIN];
    const int warp = threadIdx.x >> 6;
    const int lane = threadIdx.x & 63;
    const int n = blockIdx.x * 4 + warp;

    const T* xr = x + (size_t)n * DIN;
    xrow[warp][lane]      = ld(xr, lane);
    xrow[warp][lane + 64] = ld(xr, lane + 64);
    __syncthreads();

    float acc_e = 0.f, acc_s = 0.f;
    const int d = lane;
#pragma unroll 8
    for (int i = 0; i < DIN; ++i) {
        float xi = xrow[warp][i];
        acc_e += xi * ld(We, (size_t)i * DOUT + d);
        acc_s += xi * ld(Ws, (size_t)i * DOUT + d);
    }
    xn[(size_t)n * DOUT + d] = acc_e;
    st(h, (size_t)n * DIN + d, sigmoidf_(acc_s));
}

__global__ __launch_bounds__(256) void lin1_kernel(
    const void* __restrict__ x1, const void* __restrict__ x2,
    const void* __restrict__ We, const void* __restrict__ Ws,
    float* __restrict__ xn1, float* __restrict__ xn2,
    bf16* __restrict__ h1, bf16* __restrict__ h2,
    const int* __restrict__ flag)
{
    const int g = blockIdx.y;
    const void* x  = g ? x2 : x1;
    float*      xn = g ? xn2 : xn1;
    bf16*       h  = g ? h2 : h1;
    if (*flag) lin1_body<float>((const float*)x, (const float*)We, (const float*)Ws, xn, h);
    else       lin1_body<bf16>((const bf16*)x,  (const bf16*)We,  (const bf16*)Ws,  xn, h);
}

// ---------------------------------------------------------------------------
// Pass B: aggr = (1/K) sum_k xn[nbr[n,k]] (f32), h[:, 64:] = sigmoid(aggr)
// ---------------------------------------------------------------------------
__global__ __launch_bounds__(256) void aggr1_kernel(
    const int* __restrict__ nbr1, const int* __restrict__ nbr2,
    const float* __restrict__ xn1, const float* __restrict__ xn2,
    float* __restrict__ ag1, float* __restrict__ ag2,
    bf16* __restrict__ h1, bf16* __restrict__ h2)
{
    const int g = blockIdx.y;
    const int*   __restrict__ nbr = g ? nbr2 : nbr1;
    const float* __restrict__ xn  = g ? xn2 : xn1;
    float*       __restrict__ ag  = g ? ag2 : ag1;
    bf16*        __restrict__ h   = g ? h2 : h1;

    const int warp = threadIdx.x >> 6;
    const int lane = threadIdx.x & 63;
    const int n = blockIdx.x * 4 + warp;

    int idx_l = nbr[n * K_NBR + (lane & 15)];
    float acc = 0.f;
#pragma unroll
    for (int k = 0; k < K_NBR; ++k) {
        int idx = __shfl(idx_l, k, 64);
        acc += xn[(size_t)idx * DOUT + lane];
    }
    acc *= (1.0f / K_NBR);
    ag[(size_t)n * DOUT + lane] = acc;
    h[(size_t)n * DIN + DOUT + lane] = __float2bfloat16(sigmoidf_(acc));
}

// ---------------------------------------------------------------------------
// Pass C: fused self-attn + cross-attn -> norm1/norm2 [N,K] (f32)
// One 256-thread block per node. K x K pairwise distances in LDS.
// ---------------------------------------------------------------------------
template <typename T>
__device__ __forceinline__ void attn_body(
    const int* __restrict__ nbr1, const int* __restrict__ nbr2,
    const float* __restrict__ ag1, const float* __restrict__ ag2,
    const T* __restrict__ w_att,
    float* __restrict__ norm1, float* __restrict__ norm2)
{
    const int n = blockIdx.x;
    const int t = threadIdx.x;

    __shared__ float a1[K_NBR][DOUT + 1];
    __shared__ float a2[K_NBR][DOUT + 1];
    __shared__ float own1[DOUT], own2[DOUT], wlo[DOUT], whi[DOUT];
    __shared__ float sim[K_NBR][K_NBR + 1];
    __shared__ float rs[K_NBR], cs[K_NBR], e1[K_NBR], e2[K_NBR];
    __shared__ float red[5]; // total, si1, si2, se1, se2

#pragma unroll
    for (int r = 0; r < 4; ++r) {
        int e = t + 256 * r;
        int k = e >> 6, d = e & 63;
        a1[k][d] = ag1[(size_t)nbr1[n * K_NBR + k] * DOUT + d];
        a2[k][d] = ag2[(size_t)nbr2[n * K_NBR + k] * DOUT + d];
    }
    if (t < 64)        own1[t]       = ag1[(size_t)n * DOUT + t];
    else if (t < 128)  own2[t - 64]  = ag2[(size_t)n * DOUT + (t - 64)];
    else if (t < 192)  wlo[t - 128]  = ld(w_att, t - 128);
    else               whi[t - 192]  = ld(w_att, 64 + (t - 192));
    __syncthreads();

    {
        int k = t >> 4, l = t & 15;
        float d2 = 0.f;
#pragma unroll 8
        for (int d = 0; d < DOUT; ++d) {
            float df = a1[k][d] - a2[l][d];
            d2 += df * df;
        }
        sim[k][l] = __expf(-sqrtf(fmaxf(d2, 1e-12f)));
    }
    __syncthreads();

    if (t < 16) {                 // row sums (over l)
        float s = 0.f;
        for (int l = 0; l < 16; ++l) s += sim[t][l];
        rs[t] = s;
    } else if (t < 32) {          // col sums (over k)
        int l = t - 16; float s = 0.f;
        for (int k = 0; k < 16; ++k) s += sim[k][l];
        cs[l] = s;
    } else if (t < 48) {          // sj1[k] = a1_k . w_hi
        int k = t - 32; float s = 0.f;
        for (int d = 0; d < 64; ++d) s += a1[k][d] * whi[d];
        e1[k] = s;
    } else if (t < 64) {          // sj2[k]
        int k = t - 48; float s = 0.f;
        for (int d = 0; d < 64; ++d) s += a2[k][d] * whi[d];
        e2[k] = s;
    } else if (t == 64) {         // si1 = own1 . w_lo
        float s = 0.f;
        for (int d = 0; d < 64; ++d) s += own1[d] * wlo[d];
        red[1] = s;
    } else if (t == 65) {         // si2
        float s = 0.f;
        for (int d = 0; d < 64; ++d) s += own2[d] * wlo[d];
        red[2] = s;
    }
    __syncthreads();

    if (t < 16) {
        float v = red[1] + e1[t];
        v = v > 0.f ? v : 0.01f * v;
        e1[t] = __expf(v);
    } else if (t < 32) {
        int k = t - 16;
        float v = red[2] + e2[k];
        v = v > 0.f ? v : 0.01f * v;
        e2[k] = __expf(v);
    }
    __syncthreads();

    if (t == 0)      { float s = 0.f; for (int k = 0; k < 16; ++k) s += rs[k]; red[0] = s; }
    else if (t == 1) { float s = 0.f; for (int k = 0; k < 16; ++k) s += e1[k]; red[3] = s; }
    else if (t == 2) { float s = 0.f; for (int k = 0; k < 16; ++k) s += e2[k]; red[4] = s; }
    __syncthreads();

    if (t < 16) {
        norm1[(size_t)n * K_NBR + t] = (rs[t] / red[0]) * (e1[t] / red[3]);
    } else if (t < 32) {
        int l = t - 16;
        norm2[(size_t)n * K_NBR + l] = (cs[l] / red[0]) * (e2[l] / red[4]);
    }
}

__global__ __launch_bounds__(256) void attn_kernel(
    const int* __restrict__ nbr1, const int* __restrict__ nbr2,
    const float* __restrict__ ag1, const float* __restrict__ ag2,
    const void* __restrict__ w_att,
    float* __restrict__ norm1, float* __restrict__ norm2,
    const int* __restrict__ flag)
{
    if (*flag) attn_body<float>(nbr1, nbr2, ag1, ag2, (const float*)w_att, norm1, norm2);
    else       attn_body<bf16>(nbr1, nbr2, ag1, ag2, (const bf16*)w_att,  norm1, norm2);
}

// ---------------------------------------------------------------------------
// Pass D: he = h @ W_e2 (f32), out[:, :64] = sigmoid(h @ W_s2)
// ---------------------------------------------------------------------------
template <typename T>
__device__ __forceinline__ void lin2_body(
    const bf16* __restrict__ h, const T* __restrict__ We2, const T* __restrict__ Ws2,
    float* __restrict__ he, T* __restrict__ o)
{
    __shared__ float hrow[4][DIN];
    const int warp = threadIdx.x >> 6;
    const int lane = threadIdx.x & 63;
    const int n = blockIdx.x * 4 + warp;

    const bf16* hr = h + (size_t)n * DIN;
    hrow[warp][lane]      = b2f(hr[lane]);
    hrow[warp][lane + 64] = b2f(hr[lane + 64]);
    __syncthreads();

    float acc_e = 0.f, acc_s = 0.f;
    const int d = lane;
#pragma unroll 8
    for (int i = 0; i < DIN; ++i) {
        float xi = hrow[warp][i];
        acc_e += xi * ld(We2, (size_t)i * DOUT + d);
        acc_s += xi * ld(Ws2, (size_t)i * DOUT + d);
    }
    he[(size_t)n * DOUT + d] = acc_e;
    st(o, (size_t)n * DIN + d, sigmoidf_(acc_s));
}

__global__ __launch_bounds__(256) void lin2_kernel(
    const bf16* __restrict__ h1, const bf16* __restrict__ h2,
    const void* __restrict__ We2, const void* __restrict__ Ws2,
    float* __restrict__ he1, float* __restrict__ he2,
    void* __restrict__ out, const int* __restrict__ flag)
{
    const int g = blockIdx.y;
    const bf16* h  = g ? h2 : h1;
    float*      he = g ? he2 : he1;
    if (*flag) lin2_body<float>(h, (const float*)We2, (const float*)Ws2, he,
                                (float*)out + (size_t)g * N_NODES * DIN);
    else       lin2_body<bf16>(h, (const bf16*)We2, (const bf16*)Ws2, he,
                               (bf16*)out + (size_t)g * N_NODES * DIN);
}

// ---------------------------------------------------------------------------
// Pass E: out[:, 64:] = sigmoid(sum_k norm[n,k] * he[nbr[n,k]])
// ---------------------------------------------------------------------------
template <typename T>
__device__ __forceinline__ void aggr2_body(
    const int* __restrict__ nbr, const float* __restrict__ he,
    const float* __restrict__ nm, T* __restrict__ o)
{
    const int warp = threadIdx.x >> 6;
    const int lane = threadIdx.x & 63;
    const int n = blockIdx.x * 4 + warp;

    int   idx_l = nbr[n * K_NBR + (lane & 15)];
    float w_l   = nm[n * K_NBR + (lane & 15)];
    float acc = 0.f;
#pragma unroll
    for (int k = 0; k < K_NBR; ++k) {
        int   idx = __shfl(idx_l, k, 64);
        float w   = __shfl(w_l, k, 64);
        acc += w * he[(size_t)idx * DOUT + lane];
    }
    st(o, (size_t)n * DIN + DOUT + lane, sigmoidf_(acc));
}

__global__ __launch_bounds__(256) void aggr2_kernel(
    const int* __restrict__ nbr1, const int* __restrict__ nbr2,
    const float* __restrict__ he1, const float* __restrict__ he2,
    const float* __restrict__ nm1, const float* __restrict__ nm2,
    void* __restrict__ out, const int* __restrict__ flag)
{
    const int g = blockIdx.y;
    const int*   nbr = g ? nbr2 : nbr1;
    const float* he  = g ? he2 : he1;
    const float* nm  = g ? nm2 : nm1;
    if (*flag) aggr2_body<float>(nbr, he, nm, (float*)out + (size_t)g * N_NODES * DIN);
    else       aggr2_body<bf16>(nbr, he, nm, (bf16*)out + (size_t)g * N_NODES * DIN);
}

// ---------------------------------------------------------------------------
extern "C" void kernel_launch(void* const* d_in, const int* in_sizes, int n_in,
                              void* d_out, int out_size, void* d_ws, size_t ws_size,
                              hipStream_t stream)
{
    const void* x1   = d_in[0];
    const void* x2   = d_in[1];
    const int*  nbr1 = (const int*)d_in[2];
    const int*  nbr2 = (const int*)d_in[3];
    const void* We1  = d_in[4];
    const void* Ws1  = d_in[5];
    const void* We2  = d_in[6];
    const void* Ws2  = d_in[7];
    const void* watt = d_in[8];

    char* ws = (char*)d_ws;
    const size_t SZ64 = (size_t)N_NODES * DOUT * sizeof(float);   // 12.8 MB
    const size_t NMSZ = (size_t)N_NODES * K_NBR * sizeof(float);  //  3.2 MB
    float* xn1 = (float*)(ws + 0 * SZ64);   // later reused as he1
    float* xn2 = (float*)(ws + 1 * SZ64);   // later reused as he2
    float* ag1 = (float*)(ws + 2 * SZ64);
    float* ag2 = (float*)(ws + 3 * SZ64);
    bf16*  h1  = (bf16*) (ws + 4 * SZ64);   // N*128 bf16 = 12.8 MB
    bf16*  h2  = (bf16*) (ws + 5 * SZ64);
    float* nm1 = (float*)(ws + 6 * SZ64);
    float* nm2 = (float*)(ws + 6 * SZ64 + NMSZ);
    int*  flag = (int*)  (ws + 6 * SZ64 + 2 * NMSZ);

    dim3 b(256);
    dim3 g4(N_NODES / 4, 2);      // 12500 x 2, one wave per node

    detect_kernel<<<dim3(1), b, 0, stream>>>((const unsigned short*)x1, flag);
    lin1_kernel <<<g4, b, 0, stream>>>(x1, x2, We1, Ws1, xn1, xn2, h1, h2, flag);
    aggr1_kernel<<<g4, b, 0, stream>>>(nbr1, nbr2, xn1, xn2, ag1, ag2, h1, h2);
    attn_kernel <<<dim3(N_NODES), b, 0, stream>>>(nbr1, nbr2, ag1, ag2, watt, nm1, nm2, flag);
    lin2_kernel <<<g4, b, 0, stream>>>(h1, h2, We2, Ws2, xn1, xn2, d_out, flag);
    aggr2_kernel<<<g4, b, 0, stream>>>(nbr1, nbr2, xn1, xn2, nm1, nm2, d_out, flag);
}